// Round 1
// baseline (95.305 us; speedup 1.0000x reference)
//
#include <hip/hip_runtime.h>
#include <math.h>

#define B 128
#define N 1024
#define C 384
#define C4 96                   // C/4
#define NS 8                    // splits for ea partial pass
#define RPT (N / NS)            // 128
#define XROWS 1025
#define OUTROWS 257

typedef float f32x4 __attribute__((ext_vector_type(4)));

// workspace layout (float offsets)
#define OFF_EAP  0                       // [B][NS][C]
#define SZ_EAP   (B * NS * C)
#define OFF_NAP  (OFF_EAP + SZ_EAP)      // [B][2][C]  x-pass partial na
#define SZ_NAP   (B * 2 * C)
#define OFF_NA   (OFF_NAP + SZ_NAP)      // [B][C]
#define SZ_NA    (B * C)
#define OFF_SQ   (OFF_NA + SZ_NA)        // [0,B): sumsq(na), [B,2B): sumsq(cls)
#define SZ_SQ    (2 * B)
#define OFF_DOTS (OFF_SQ + SZ_SQ)        // [B][N] per-row channel_aggregation
#define SZ_DOTS  (B * N)

__device__ __forceinline__ float sigmoidf(float v) { return 1.f / (1.f + expf(-v)); }
__device__ __forceinline__ float dot4v(f32x4 a, f32x4 b) {
    return a.x * b.x + a.y * b.y + a.z * b.z + a.w * b.w;
}

// ---------------- kA: partial column sums of edge_aggregation (f32x4, nontemporal) --------------
// grid (B, NS) x 384 : 1024 blocks -> full-machine streaming of ea (201 MB)
__global__ __launch_bounds__(384) void kA_ea_partial(const float* __restrict__ ea,
                                                     float* __restrict__ eaP) {
    int b = blockIdx.x, s = blockIdx.y, t = threadIdx.x;
    int rg = t / C4, c4 = t % C4;
    const f32x4* p = (const f32x4*)(ea + ((size_t)b * N + (size_t)s * RPT) * C);
    f32x4 acc = (f32x4)(0.f);
#pragma unroll 8
    for (int it = 0; it < RPT / 4; ++it)
        acc += __builtin_nontemporal_load(&p[(size_t)(it * 4 + rg) * C4 + c4]);
    __shared__ f32x4 lds[4][C4];
    lds[rg][c4] = acc;
    __syncthreads();
    if (t < C4) {
        f32x4 r = lds[0][t] + lds[1][t] + lds[2][t] + lds[3][t];
        ((f32x4*)(eaP + ((size_t)b * NS + s) * C))[t] = r;
    }
}

// ---------------- kB: x-pass on the FULL machine: grid (B, 2) x 1024 -------------------------
// each block: ci from eaP (L2-hot), then 512 rows: per-row dot -> dots ws,
// sigmoid-weighted partial accumulation -> naP ws.
__global__ __launch_bounds__(1024) void kB_xpass(const float* __restrict__ x,
                                                 const float* __restrict__ eaP,
                                                 float* __restrict__ naP,
                                                 float* __restrict__ dotsG) {
    int b = blockIdx.x, sb = blockIdx.y, tid = threadIdx.x;
    int w = tid >> 6, lane = tid & 63, hl = lane & 31, half = lane >> 5;

    __shared__ float sci[C];                // 1.5 KB
    __shared__ f32x4 sacc[16][C4];          // 24 KB

    // ci = sigmoid(mean) from the NS eaP partials (12 KB per block, L2-hot)
    if (tid < C4) {
        const f32x4* ep = (const f32x4*)(eaP + (size_t)b * NS * C);
        f32x4 s = (f32x4)(0.f);
#pragma unroll
        for (int r = 0; r < NS; ++r) s += ep[(size_t)r * C4 + tid];
        s *= (1.f / (float)N);
        sci[4 * tid + 0] = sigmoidf(s.x);
        sci[4 * tid + 1] = sigmoidf(s.y);
        sci[4 * tid + 2] = sigmoidf(s.z);
        sci[4 * tid + 3] = sigmoidf(s.w);
    }
    __syncthreads();

    f32x4 cir[3];
#pragma unroll
    for (int k = 0; k < 3; ++k) cir[k] = ((const f32x4*)sci)[hl + 32 * k];
    f32x4 acc[3];
#pragma unroll
    for (int k = 0; k < 3; ++k) acc[k] = (f32x4)(0.f);

    // this block's 512 rows
    const float* xb = x + (size_t)b * XROWS * C + C + (size_t)sb * 512 * C;
#pragma unroll 2
    for (int it = 0; it < 16; ++it) {
        int r = 32 * it + 2 * w + half;
        const f32x4* rp = (const f32x4*)(xb + (size_t)r * C);
        f32x4 v[3];
        float dotv = 0.f;
#pragma unroll
        for (int k = 0; k < 3; ++k) {
            v[k] = rp[hl + 32 * k];
            dotv += dot4v(v[k], cir[k]);
        }
#pragma unroll
        for (int off = 16; off > 0; off >>= 1) dotv += __shfl_xor(dotv, off, 64);
        if (hl == 0) dotsG[(size_t)b * N + sb * 512 + r] = dotv;
        float si = sigmoidf(dotv);
#pragma unroll
        for (int k = 0; k < 3; ++k) acc[k] += si * v[k];
    }
#pragma unroll
    for (int k = 0; k < 3; ++k) {
        acc[k].x += __shfl_xor(acc[k].x, 32, 64);
        acc[k].y += __shfl_xor(acc[k].y, 32, 64);
        acc[k].z += __shfl_xor(acc[k].z, 32, 64);
        acc[k].w += __shfl_xor(acc[k].w, 32, 64);
    }
    if (half == 0) {
#pragma unroll
        for (int k = 0; k < 3; ++k) sacc[w][hl + 32 * k] = acc[k];
    }
    __syncthreads();

    if (tid < C4) {
        f32x4 s = (f32x4)(0.f);
#pragma unroll
        for (int w2 = 0; w2 < 16; ++w2) s += sacc[w2][tid];
        ((f32x4*)(naP + ((size_t)b * 2 + sb) * C))[tid] = s;
    }
}

// ---------------- kC: sort + gather on the FULL machine: grid (B, 2) x 1024 ------------------
// both sub-blocks redundantly sort the 1024 dots; sub-block g gathers outpos
// [g*128, (g+1)*128). sub-block 0 also reduces naP -> na and emits sumsq pair.
__global__ __launch_bounds__(1024) void kC_sort_gather(const float* __restrict__ x,
                                                       const float* __restrict__ cls,
                                                       const float* __restrict__ naP,
                                                       const float* __restrict__ dotsG,
                                                       float* __restrict__ na,
                                                       float* __restrict__ sqp,
                                                       float* __restrict__ out) {
    int b = blockIdx.x, g = blockIdx.y, tid = threadIdx.x;
    int w = tid >> 6, lane = tid & 63;

    __shared__ unsigned long long bufA[N];  // 8 KB
    __shared__ unsigned long long bufB[N];  // 8 KB
    __shared__ unsigned llist[256];         // 1 KB
    __shared__ float escr[2 * C4];          // 768 B

    // ---------- na reduce + per-batch sumsq (sub-block 0 only; block-uniform branch) ----------
    if (g == 0) {
        if (tid < C4) {
            const f32x4* p0 = (const f32x4*)(naP + (size_t)b * 2 * C);
            const f32x4* p1 = (const f32x4*)(naP + ((size_t)b * 2 + 1) * C);
            f32x4 s = p0[tid] + p1[tid];
            ((f32x4*)(na + (size_t)b * C))[tid] = s;
            escr[tid] = dot4v(s, s);
            f32x4 cv = ((const f32x4*)(cls + (size_t)b * C))[tid];
            escr[C4 + tid] = dot4v(cv, cv);
        }
        __syncthreads();
        if (w == 0) {
            float nss = (lane < 32) ? (escr[lane] + escr[lane + 32] + escr[lane + 64]) : 0.f;
            float css = (lane < 32) ? (escr[C4 + lane] + escr[C4 + lane + 32] + escr[C4 + lane + 64]) : 0.f;
#pragma unroll
            for (int off = 32; off > 0; off >>= 1) {
                nss += __shfl_xor(nss, off, 64);
                css += __shfl_xor(css, off, 64);
            }
            if (lane == 0) { sqp[b] = nss; sqp[B + b] = css; }
        }
    }

    // ---------- u64-key bitonic sort (stable ascending argsort) ----------
    float vv = dotsG[(size_t)b * N + tid];
    unsigned u = __float_as_uint(vv);
    u = (u & 0x80000000u) ? ~u : (u | 0x80000000u);
    unsigned long long key = ((unsigned long long)u << 32) | (unsigned)tid;

    bool useA = true;
    for (int k = 2; k <= N; k <<= 1) {
        bool up = ((tid & k) == 0);
        for (int j = k >> 1; j > 0; j >>= 1) {
            unsigned long long other;
            if (j < 64) {
                other = __shfl_xor(key, j, 64);
            } else {
                unsigned long long* buf = useA ? bufA : bufB;
                useA = !useA;
                buf[tid] = key;
                __syncthreads();
                other = buf[tid ^ j];
            }
            bool iAmLow = ((tid & j) == 0);
            bool keepMin = (iAmLow == up);
            bool otherLess = (other < key);
            key = (keepMin == otherLess) ? other : key;
        }
    }
    __syncthreads();   // drain last LDS-stage reads

    // ---------- node-ascending (node, outpos) list ----------
    unsigned* flag = (unsigned*)bufA;
    unsigned* wsum = (unsigned*)bufB;
    flag[tid] = 0;
    __syncthreads();
    if (tid >= 768) flag[(unsigned)(key & 1023u)] = (unsigned)(tid - 768) | 0x80000000u;
    __syncthreads();
    unsigned f = flag[tid];
    bool sel = (f & 0x80000000u) != 0;
    unsigned long long bal = __ballot(sel);
    if (lane == 0) wsum[w] = (unsigned)__popcll(bal);
    __syncthreads();
    if (sel) {
        int base = 0;
        for (int w2 = 0; w2 < w; ++w2) base += (int)wsum[w2];
        int intra = (int)__popcll(bal & ((1ull << lane) - 1ull));
        llist[base + intra] = ((unsigned)tid << 8) | (f & 0xFFu);
    }
    __syncthreads();

    // ---------- gather 128 pooled rows per sub-block (x rows L3-warm from kB) ----------
    const float* xb2 = x + ((size_t)b * XROWS + 1) * C;
#pragma unroll 4
    for (int q = 0; q < 12; ++q) {
        int e = tid + 1024 * q;
        int lp = 128 * g + e / C4, c4 = e % C4;
        unsigned ent = llist[lp];
        int node = (int)(ent >> 8);
        int op = (int)(ent & 0xFFu);
        f32x4 sv = *((const f32x4*)(xb2 + (size_t)node * C) + c4);
        __builtin_nontemporal_store(sv,
            (f32x4*)(out + ((size_t)b * OUTROWS + 1 + op) * C) + c4);
    }
}

// ---------------- kZ: finish global norms, write out[:,0,:] ----------------
__global__ __launch_bounds__(384) void kZ_cls(const float* __restrict__ sqp,
                                              const float* __restrict__ cls,
                                              const float* __restrict__ na,
                                              float* __restrict__ out) {
    int b = blockIdx.x, t = threadIdx.x;
    __shared__ float2 red[128];
    if (t < 128) red[t] = make_float2(sqp[t], sqp[B + t]);
    __syncthreads();
    for (int o = 64; o > 0; o >>= 1) {
        if (t < o) {
            float2 a = red[t], d = red[t + o];
            red[t] = make_float2(a.x + d.x, a.y + d.y);
        }
        __syncthreads();
    }
    float ratio = sqrtf(red[0].y / red[0].x);  // ||cls|| / ||na||
    out[((size_t)b * OUTROWS) * C + t] =
        cls[(size_t)b * C + t] + ratio * na[(size_t)b * C + t];
}

extern "C" void kernel_launch(void* const* d_in, const int* in_sizes, int n_in,
                              void* d_out, int out_size, void* d_ws, size_t ws_size,
                              hipStream_t stream) {
    const float* x   = (const float*)d_in[0];
    const float* cls = (const float*)d_in[1];
    const float* ea  = (const float*)d_in[2];
    float* out = (float*)d_out;
    float* ws  = (float*)d_ws;

    float* eaP   = ws + OFF_EAP;
    float* naP   = ws + OFF_NAP;
    float* na    = ws + OFF_NA;
    float* sqp   = ws + OFF_SQ;
    float* dotsG = ws + OFF_DOTS;

    kA_ea_partial<<<dim3(B, NS), 384, 0, stream>>>(ea, eaP);
    kB_xpass<<<dim3(B, 2), 1024, 0, stream>>>(x, eaP, naP, dotsG);
    kC_sort_gather<<<dim3(B, 2), 1024, 0, stream>>>(x, cls, naP, dotsG, na, sqp, out);
    kZ_cls<<<B, 384, 0, stream>>>(sqp, cls, na, out);
}

// Round 2
// 92.691 us; speedup vs baseline: 1.0282x; 1.0282x over previous
//
#include <hip/hip_runtime.h>
#include <math.h>

#define B 128
#define N 1024
#define C 384
#define C4 96                   // C/4
#define XROWS 1025
#define OUTROWS 257

typedef float f32x4 __attribute__((ext_vector_type(4)));

// workspace layout (float offsets)
#define OFF_NA   0                       // [B][C]
#define SZ_NA    (B * C)
#define OFF_SQ   (OFF_NA + SZ_NA)        // [0,B): sumsq(na), [B,2B): sumsq(cls)
#define SZ_SQ    (2 * B)

__device__ __forceinline__ float sigmoidf(float v) { return 1.f / (1.f + expf(-v)); }
__device__ __forceinline__ float dot4v(f32x4 a, f32x4 b) {
    return a.x * b.x + a.y * b.y + a.z * b.z + a.w * b.w;
}

// ---------------- fatk: 1 block/batch, fully fused ----------------
// phase0: ea column-sum (own batch, 1.57 MB, nontemporal) -> ci
// phase1: x-pass (per-row dot -> dots, sigmoid-weighted accumulate -> na, sumsq)
// phase2: u64 bitonic argsort of dots
// phase3: gather 256 pooled rows (x L2-hot from phase1 on the SAME CU)
__global__ __launch_bounds__(1024) void fatk(const float* __restrict__ x,
                                             const float* __restrict__ cls,
                                             const float* __restrict__ ea,
                                             float* __restrict__ na,
                                             float* __restrict__ sqp,
                                             float* __restrict__ out) {
    int b = blockIdx.x, tid = threadIdx.x;
    int w = tid >> 6, lane = tid & 63, hl = lane & 31, half = lane >> 5;

    __shared__ float sci[C];                // 1.5 KB
    __shared__ float dots[N];               // 4 KB
    __shared__ f32x4 sacc[16][C4];          // 24 KB
    __shared__ unsigned long long bufA[N];  // 8 KB
    __shared__ unsigned long long bufB[N];  // 8 KB
    __shared__ unsigned llist[256];         // 1 KB
    __shared__ float escr[2 * C4];          // 768 B   (~47.3 KB total)

    // ---------- phase 0: ea column sums over this batch's 1024 rows ----------
    {
        const float* eb = ea + (size_t)b * N * C;
        f32x4 eacc[3];
#pragma unroll
        for (int k = 0; k < 3; ++k) eacc[k] = (f32x4)(0.f);
#pragma unroll 2
        for (int it = 0; it < 32; ++it) {
            int r = 32 * it + 2 * w + half;
            const f32x4* rp = (const f32x4*)(eb + (size_t)r * C);
#pragma unroll
            for (int k = 0; k < 3; ++k)
                eacc[k] += __builtin_nontemporal_load(&rp[hl + 32 * k]);
        }
#pragma unroll
        for (int k = 0; k < 3; ++k) {
            eacc[k].x += __shfl_xor(eacc[k].x, 32, 64);
            eacc[k].y += __shfl_xor(eacc[k].y, 32, 64);
            eacc[k].z += __shfl_xor(eacc[k].z, 32, 64);
            eacc[k].w += __shfl_xor(eacc[k].w, 32, 64);
        }
        if (half == 0) {
#pragma unroll
            for (int k = 0; k < 3; ++k) sacc[w][hl + 32 * k] = eacc[k];
        }
    }
    __syncthreads();
    if (tid < C4) {
        f32x4 s = (f32x4)(0.f);
#pragma unroll
        for (int w2 = 0; w2 < 16; ++w2) s += sacc[w2][tid];
        s *= (1.f / (float)N);
        sci[4 * tid + 0] = sigmoidf(s.x);
        sci[4 * tid + 1] = sigmoidf(s.y);
        sci[4 * tid + 2] = sigmoidf(s.z);
        sci[4 * tid + 3] = sigmoidf(s.w);
    }
    __syncthreads();   // sci ready; also guards sacc reuse by phase 1

    // ---------- phase 1: x-pass (dot + sigmoid-weighted accumulate) ----------
    f32x4 cir[3];
#pragma unroll
    for (int k = 0; k < 3; ++k) cir[k] = ((const f32x4*)sci)[hl + 32 * k];
    f32x4 acc[3];
#pragma unroll
    for (int k = 0; k < 3; ++k) acc[k] = (f32x4)(0.f);

    const float* xb = x + (size_t)b * XROWS * C + C;   // nodes base (skip cls row)
#pragma unroll 2
    for (int it = 0; it < 32; ++it) {
        int r = 32 * it + 2 * w + half;
        const f32x4* rp = (const f32x4*)(xb + (size_t)r * C);
        f32x4 v[3];
        float dotv = 0.f;
#pragma unroll
        for (int k = 0; k < 3; ++k) {
            v[k] = rp[hl + 32 * k];
            dotv += dot4v(v[k], cir[k]);
        }
#pragma unroll
        for (int off = 16; off > 0; off >>= 1) dotv += __shfl_xor(dotv, off, 64);
        if (hl == 0) dots[r] = dotv;
        float si = sigmoidf(dotv);
#pragma unroll
        for (int k = 0; k < 3; ++k) acc[k] += si * v[k];
    }
#pragma unroll
    for (int k = 0; k < 3; ++k) {
        acc[k].x += __shfl_xor(acc[k].x, 32, 64);
        acc[k].y += __shfl_xor(acc[k].y, 32, 64);
        acc[k].z += __shfl_xor(acc[k].z, 32, 64);
        acc[k].w += __shfl_xor(acc[k].w, 32, 64);
    }
    if (half == 0) {
#pragma unroll
        for (int k = 0; k < 3; ++k) sacc[w][hl + 32 * k] = acc[k];
    }
    __syncthreads();

    // ---------- na reduce + per-batch sumsq(na), sumsq(cls) ----------
    if (tid < C4) {
        f32x4 s = (f32x4)(0.f);
#pragma unroll
        for (int w2 = 0; w2 < 16; ++w2) s += sacc[w2][tid];
        ((f32x4*)(na + (size_t)b * C))[tid] = s;
        escr[tid] = dot4v(s, s);
        f32x4 cv = ((const f32x4*)(cls + (size_t)b * C))[tid];
        escr[C4 + tid] = dot4v(cv, cv);
    }
    __syncthreads();
    if (w == 0) {
        float nss = (lane < 32) ? (escr[lane] + escr[lane + 32] + escr[lane + 64]) : 0.f;
        float css = (lane < 32) ? (escr[C4 + lane] + escr[C4 + lane + 32] + escr[C4 + lane + 64]) : 0.f;
#pragma unroll
        for (int off = 32; off > 0; off >>= 1) {
            nss += __shfl_xor(nss, off, 64);
            css += __shfl_xor(css, off, 64);
        }
        if (lane == 0) { sqp[b] = nss; sqp[B + b] = css; }
    }

    // ---------- phase 2: u64-key bitonic sort (stable ascending argsort) ----------
    float vv = dots[tid];
    unsigned u = __float_as_uint(vv);
    u = (u & 0x80000000u) ? ~u : (u | 0x80000000u);
    unsigned long long key = ((unsigned long long)u << 32) | (unsigned)tid;

    bool useA = true;
    for (int k = 2; k <= N; k <<= 1) {
        bool up = ((tid & k) == 0);
        for (int j = k >> 1; j > 0; j >>= 1) {
            unsigned long long other;
            if (j < 64) {
                other = __shfl_xor(key, j, 64);
            } else {
                unsigned long long* buf = useA ? bufA : bufB;
                useA = !useA;
                buf[tid] = key;
                __syncthreads();
                other = buf[tid ^ j];
            }
            bool iAmLow = ((tid & j) == 0);
            bool keepMin = (iAmLow == up);
            bool otherLess = (other < key);
            key = (keepMin == otherLess) ? other : key;
        }
    }
    __syncthreads();   // drain last LDS-stage reads

    // ---------- node-ascending (node, outpos) list ----------
    unsigned* flag = (unsigned*)bufA;
    unsigned* wsum = (unsigned*)bufB;
    flag[tid] = 0;
    __syncthreads();
    if (tid >= 768) flag[(unsigned)(key & 1023u)] = (unsigned)(tid - 768) | 0x80000000u;
    __syncthreads();
    unsigned f = flag[tid];
    bool sel = (f & 0x80000000u) != 0;
    unsigned long long bal = __ballot(sel);
    if (lane == 0) wsum[w] = (unsigned)__popcll(bal);
    __syncthreads();
    if (sel) {
        int base = 0;
        for (int w2 = 0; w2 < w; ++w2) base += (int)wsum[w2];
        int intra = (int)__popcll(bal & ((1ull << lane) - 1ull));
        llist[base + intra] = ((unsigned)tid << 8) | (f & 0xFFu);
    }
    __syncthreads();

    // ---------- phase 3: gather 256 pooled rows (x L2-hot from phase 1) ----------
    const float* xb2 = x + ((size_t)b * XROWS + 1) * C;
#pragma unroll 4
    for (int q = 0; q < 24; ++q) {
        int e = tid + 1024 * q;
        int lp = e / C4, c4 = e % C4;
        unsigned ent = llist[lp];
        int node = (int)(ent >> 8);
        int op = (int)(ent & 0xFFu);
        f32x4 sv = *((const f32x4*)(xb2 + (size_t)node * C) + c4);
        __builtin_nontemporal_store(sv,
            (f32x4*)(out + ((size_t)b * OUTROWS + 1 + op) * C) + c4);
    }
}

// ---------------- kZ: finish global norms, write out[:,0,:] ----------------
__global__ __launch_bounds__(384) void kZ_cls(const float* __restrict__ sqp,
                                              const float* __restrict__ cls,
                                              const float* __restrict__ na,
                                              float* __restrict__ out) {
    int b = blockIdx.x, t = threadIdx.x;
    __shared__ float2 red[128];
    if (t < 128) red[t] = make_float2(sqp[t], sqp[B + t]);
    __syncthreads();
    for (int o = 64; o > 0; o >>= 1) {
        if (t < o) {
            float2 a = red[t], d = red[t + o];
            red[t] = make_float2(a.x + d.x, a.y + d.y);
        }
        __syncthreads();
    }
    float ratio = sqrtf(red[0].y / red[0].x);  // ||cls|| / ||na||
    out[((size_t)b * OUTROWS) * C + t] =
        cls[(size_t)b * C + t] + ratio * na[(size_t)b * C + t];
}

extern "C" void kernel_launch(void* const* d_in, const int* in_sizes, int n_in,
                              void* d_out, int out_size, void* d_ws, size_t ws_size,
                              hipStream_t stream) {
    const float* x   = (const float*)d_in[0];
    const float* cls = (const float*)d_in[1];
    const float* ea  = (const float*)d_in[2];
    float* out = (float*)d_out;
    float* ws  = (float*)d_ws;

    float* na  = ws + OFF_NA;
    float* sqp = ws + OFF_SQ;

    fatk<<<B, 1024, 0, stream>>>(x, cls, ea, na, sqp, out);
    kZ_cls<<<B, 384, 0, stream>>>(sqp, cls, na, out);
}